// Round 12
// baseline (45.259 us; speedup 1.0000x reference)
//
#include <hip/hip_runtime.h>

#define NN 1024
#define BB 64
#define CHUNKS 16
#define KS 8   // k-splits per batch in the DFT kernel

// ---------------------------------------------------------------------------
// Kernel 1: balanced diagonal partial sums, v7 (CHUNKS=16, 8 pairs/wave).
// Block t pairs 32 LONG rows [32t,32t+32) with 32 SHORT rows
// [992-32t, 992-32t+32). Wave w takes rows ≡ w (mod 4): r = w constant.
// Pair index kk = 0..7: top row i = 32t + w + 4*kk (nvT = 256-8t-kk ∈ [129,256]),
// bottom row i = 992-32t + w + 4*kk (nvB = 8+8t-kk ∈ [1,128]).
// Fixed (lane,group,comp)->d register map: d = 4*(lane+64*g) + comp - w.
// Depth-3 pipeline per half: L L L C L C C C.
__global__ __launch_bounds__(256) void diag_partial(const float* __restrict__ attns,
                                                    float* __restrict__ partial,
                                                    unsigned* __restrict__ counter) {
    __shared__ float lds[4][1032];
    const int t = blockIdx.x;       // 0..15
    const int b = blockIdx.y;
    const int tid = threadIdx.x;
    const int w = tid >> 6, lane = tid & 63;

    if (t == 0 && b == 0 && tid == 0) *counter = 0u;   // reset ticket for dft

    float4 acc0 = make_float4(0.f, 0.f, 0.f, 0.f);
    float4 acc1 = acc0, acc2 = acc0, acc3 = acc0;

    const float* base = attns + (size_t)b * NN * NN;

// g = literal suffix 0..3, kk = pair index expression
#define ROWPAIR(g, kk)                                                        \
    const int jbT##g = 32 * t + 4 * (kk);                                     \
    const int nvT##g = 256 - 8 * t - (kk);                                    \
    const float4* fT##g = (const float4*)(base + (size_t)(jbT##g + w) * NN + jbT##g); \
    const int jbB##g = 992 - 32 * t + 4 * (kk);                               \
    const int nvB##g = 8 + 8 * t - (kk);                                      \
    const float4* fB##g = (const float4*)(base + (size_t)(jbB##g + w) * NN + jbB##g);

#define LOADP(g)                                                              \
    float4 xa##g = fT##g[lane];                                               \
    float4 xb##g = fT##g[lane + 64];                                          \
    float4 xc##g = fT##g[lane + 128 < nvT##g - 1 ? lane + 128 : nvT##g - 1];  \
    float4 xd##g = fT##g[lane + 192 < nvT##g - 1 ? lane + 192 : nvT##g - 1];  \
    float4 ya##g = fB##g[lane < nvB##g - 1 ? lane : nvB##g - 1];              \
    float4 yb##g = fB##g[lane + 64 < nvB##g - 1 ? lane + 64 : nvB##g - 1];

#define CONSP(g)                                                              \
    {                                                                         \
        const bool ok2 = lane + 128 < nvT##g, ok3 = lane + 192 < nvT##g;      \
        const bool p0 = lane < nvB##g, p1 = lane + 64 < nvB##g;               \
        xc##g.x = ok2 ? xc##g.x : 0.f; xc##g.y = ok2 ? xc##g.y : 0.f;         \
        xc##g.z = ok2 ? xc##g.z : 0.f; xc##g.w = ok2 ? xc##g.w : 0.f;         \
        xd##g.x = ok3 ? xd##g.x : 0.f; xd##g.y = ok3 ? xd##g.y : 0.f;         \
        xd##g.z = ok3 ? xd##g.z : 0.f; xd##g.w = ok3 ? xd##g.w : 0.f;         \
        ya##g.x = p0 ? ya##g.x : 0.f; ya##g.y = p0 ? ya##g.y : 0.f;           \
        ya##g.z = p0 ? ya##g.z : 0.f; ya##g.w = p0 ? ya##g.w : 0.f;           \
        yb##g.x = p1 ? yb##g.x : 0.f; yb##g.y = p1 ? yb##g.y : 0.f;           \
        yb##g.z = p1 ? yb##g.z : 0.f; yb##g.w = p1 ? yb##g.w : 0.f;           \
        if (lane == 0) {                                                      \
            if (w > 0) { xa##g.x = 0.f; ya##g.x = 0.f; }                      \
            if (w > 1) { xa##g.y = 0.f; ya##g.y = 0.f; }                      \
            if (w > 2) { xa##g.z = 0.f; ya##g.z = 0.f; }                      \
        }                                                                     \
        acc0.x += xa##g.x + ya##g.x; acc0.y += xa##g.y + ya##g.y;             \
        acc0.z += xa##g.z + ya##g.z; acc0.w += xa##g.w + ya##g.w;             \
        acc1.x += xb##g.x + yb##g.x; acc1.y += xb##g.y + yb##g.y;             \
        acc1.z += xb##g.z + yb##g.z; acc1.w += xb##g.w + yb##g.w;             \
        acc2.x += xc##g.x; acc2.y += xc##g.y;                                 \
        acc2.z += xc##g.z; acc2.w += xc##g.w;                                 \
        acc3.x += xd##g.x; acc3.y += xd##g.y;                                 \
        acc3.z += xd##g.z; acc3.w += xd##g.w;                                 \
    }

#define HALFBODY(K0)                                                          \
    {                                                                         \
        ROWPAIR(0, (K0) + 0)                                                  \
        ROWPAIR(1, (K0) + 1)                                                  \
        ROWPAIR(2, (K0) + 2)                                                  \
        ROWPAIR(3, (K0) + 3)                                                  \
        LOADP(0)                                                              \
        LOADP(1)                                                              \
        LOADP(2)                                                              \
        CONSP(0)                                                              \
        LOADP(3)                                                              \
        CONSP(1)                                                              \
        CONSP(2)                                                              \
        CONSP(3)                                                              \
    }

    HALFBODY(0)
    HALFBODY(4)
#undef ROWPAIR
#undef LOADP
#undef CONSP
#undef HALFBODY

    // dump: lds[w][4*(lane+64*g)+comp] — bijective onto [0,1024) per wave
    float4* lrow = (float4*)lds[w];
    lrow[lane]       = acc0;
    lrow[lane + 64]  = acc1;
    lrow[lane + 128] = acc2;
    lrow[lane + 192] = acc3;
    if (tid < 32) lds[tid >> 3][1024 + (tid & 7)] = 0.f;
    __syncthreads();

    // partial[b][t][d] = sum over waves of lds[wv][d + wv]; float4 store
    float* outp = partial + ((size_t)b * CHUNKS + t) * NN;
    {
        const int d0 = tid * 4;
        float4 o;
        o.x = (lds[0][d0]     + lds[1][d0 + 1]) + (lds[2][d0 + 2] + lds[3][d0 + 3]);
        o.y = (lds[0][d0 + 1] + lds[1][d0 + 2]) + (lds[2][d0 + 3] + lds[3][d0 + 4]);
        o.z = (lds[0][d0 + 2] + lds[1][d0 + 3]) + (lds[2][d0 + 4] + lds[3][d0 + 5]);
        o.w = (lds[0][d0 + 3] + lds[1][d0 + 4]) + (lds[2][d0 + 5] + lds[3][d0 + 6]);
        ((float4*)outp)[tid] = o;
    }
}

// ---------------------------------------------------------------------------
// Kernel 2: reduce chunk partials -> parity-split means (CHUNKS=16).
// 512 blocks x 256 thr: block (b, dq of 64 d); thread (d, c-quarter) sums 4
// chunks; 4->1 combine via LDS.
__global__ __launch_bounds__(256) void reduce_waves(const float* __restrict__ partial,
                                                    float* __restrict__ wpm) {
    __shared__ float slo_s[256], shi_s[256];
    const int blk = blockIdx.x;
    const int b = blk >> 3;
    const int dq = blk & 7;
    const int tid = threadIdx.x;
    const int d = dq * 64 + (tid & 63);
    const int cq = tid >> 6;            // 0..3
    const float* pb = partial + (size_t)b * CHUNKS * NN;
    float slo = 0.f, shi = 0.f;
#pragma unroll
    for (int j = 0; j < 4; ++j) {
        const int c = cq * 4 + j;
        slo += pb[c * NN + d];
        shi += pb[c * NN + d + 512];
    }
    slo_s[tid] = slo; shi_s[tid] = shi;
    __syncthreads();
    if (tid < 64) {
        const float l = (slo_s[tid] + slo_s[tid + 64]) + (slo_s[tid + 128] + slo_s[tid + 192]);
        const float h = (shi_s[tid] + shi_s[tid + 64]) + (shi_s[tid + 128] + shi_s[tid + 192]);
        const float wlo = l / (float)(NN - d);
        const float whi = h / (float)(512 - d);
        wpm[(size_t)b * NN + d]       = wlo + whi;   // wp
        wpm[(size_t)b * NN + 512 + d] = wlo - whi;   // wm
    }
}

// ---------------------------------------------------------------------------
// Kernel 3: even/odd-decimated DFT + ticketed finalize.
__global__ __launch_bounds__(512) void dft_part(const float* __restrict__ wpm,
                                                float* __restrict__ kparts,
                                                unsigned* __restrict__ counter,
                                                float* __restrict__ out,
                                                int nblocks) {
    __shared__ float wp[512], wm[512];
    __shared__ float2 tw[NN];       // (cos, -sin)
    __shared__ float redmax[8], redsum[8];
    __shared__ int lastFlag;
    const int ks = blockIdx.x & (KS - 1);
    const int b = blockIdx.x >> 3;
    const int tid = threadIdx.x;
    const float C = 6.283185307179586f / 1024.0f;

    {
        const float* src = wpm + (size_t)b * NN;
        wp[tid & 511] = src[tid & 511];
        wm[tid & 511] = src[512 + (tid & 511)];
        float s0, c0, s1, c1;
        __sincosf((float)tid * C, &s0, &c0);
        __sincosf((float)(tid + 512) * C, &s1, &c1);
        tw[tid]       = make_float2(c0, -s0);
        tw[tid + 512] = make_float2(c1, -s1);
    }
    __syncthreads();

    const int k = 1 + ks * 64 + (tid >> 3);
    const int dp = tid & 7;
    const float* wsel = (k & 1) ? wm : wp;
    const int kstep = (k << 3) & (NN - 1);

    float re = 0.f, im = 0.f;
    int t = (k * dp) & (NN - 1);
#pragma unroll 8
    for (int it = 0; it < 64; ++it) {
        const float2 c = tw[t];
        const float wv = wsel[dp + 8 * it];
        re = fmaf(wv, c.x, re);
        im = fmaf(wv, c.y, im);
        t = (t + kstep) & (NN - 1);
    }
    re += __shfl_xor(re, 1, 64); re += __shfl_xor(re, 2, 64); re += __shfl_xor(re, 4, 64);
    im += __shfl_xor(im, 1, 64); im += __shfl_xor(im, 2, 64); im += __shfl_xor(im, 4, 64);
    const float spec = sqrtf(re * re + im * im);

    float mx = spec;
    float sm = (dp == 0) ? spec : 0.f;
    for (int off = 8; off < 64; off <<= 1) {
        mx = fmaxf(mx, __shfl_xor(mx, off, 64));
        sm += __shfl_xor(sm, off, 64);
    }
    const int wid = tid >> 6, lane = tid & 63;
    if (lane == 0) { redmax[wid] = mx; redsum[wid] = sm; }
    __syncthreads();

    if (tid == 0) {
        float M = redmax[0], S = redsum[0];
        for (int i = 1; i < 8; ++i) { M = fmaxf(M, redmax[i]); S += redsum[i]; }
        __hip_atomic_store(&kparts[((size_t)b * KS + ks) * 2 + 0], M,
                           __ATOMIC_RELAXED, __HIP_MEMORY_SCOPE_AGENT);
        __hip_atomic_store(&kparts[((size_t)b * KS + ks) * 2 + 1], S,
                           __ATOMIC_RELAXED, __HIP_MEMORY_SCOPE_AGENT);
        const unsigned ticket = __hip_atomic_fetch_add(counter, 1u,
                                   __ATOMIC_ACQ_REL, __HIP_MEMORY_SCOPE_AGENT);
        lastFlag = (ticket == (unsigned)(nblocks - 1));
    }
    __syncthreads();

    if (lastFlag && tid < 64) {
        float M = 0.f, S = 0.f;
#pragma unroll
        for (int s = 0; s < KS; ++s) {
            M = fmaxf(M, __hip_atomic_load(&kparts[((size_t)tid * KS + s) * 2 + 0],
                                           __ATOMIC_RELAXED, __HIP_MEMORY_SCOPE_AGENT));
            S += __hip_atomic_load(&kparts[((size_t)tid * KS + s) * 2 + 1],
                                   __ATOMIC_RELAXED, __HIP_MEMORY_SCOPE_AGENT);
        }
        float j = 1.0f - M / S;
        for (int off = 32; off; off >>= 1) j += __shfl_xor(j, off, 64);
        if (tid == 0) out[0] = j * (1.0f / 64.0f);
    }
}

// ---------------------------------------------------------------------------
extern "C" void kernel_launch(void* const* d_in, const int* in_sizes, int n_in,
                              void* d_out, int out_size, void* d_ws, size_t ws_size,
                              hipStream_t stream) {
    const float* attns = (const float*)d_in[0];
    float* out = (float*)d_out;

    // workspace: [partial: B*CHUNKS*N = 4MB] [wpm: B*N] [kparts: B*KS*2] [counter]
    float* partial    = (float*)d_ws;
    float* wpm        = partial + (size_t)BB * CHUNKS * NN;
    float* kparts     = wpm + (size_t)BB * NN;
    unsigned* counter = (unsigned*)(kparts + (size_t)BB * KS * 2);

    diag_partial<<<dim3(CHUNKS, BB), 256, 0, stream>>>(attns, partial, counter);
    reduce_waves<<<BB * 8, 256, 0, stream>>>(partial, wpm);
    const int nblocks = BB * KS;
    dft_part<<<nblocks, 512, 0, stream>>>(wpm, kparts, counter, out, nblocks);
}